// Round 6
// baseline (838.003 us; speedup 1.0000x reference)
//
#include <hip/hip_runtime.h>
#include <hip/hip_bf16.h>

// APPNP: h = MLP(x); h_{t+1} = 0.9 * (D^-1/2 (A+I) D^-1/2) h_t + 0.1 * h0, K=10
// Round 5 (this session):
//  - GEMM1: counted-vmcnt 2-phase pipeline (T3/T4). Double-buffered LDS
//    (A 2x8KB + B 2x16KB = 48KB); stage(t+1) issued before compute(t);
//    raw s_barrier + "s_waitcnt vmcnt(8)" so next tile's 8 loads stay in
//    flight across the barrier (hipcc's __syncthreads drains vmcnt(0) --
//    that drain was 92% of gemm1 time: MfmaUtil 7.9%, nothing else busy).
//    fp32-A path: float4->regs issued early, cvt+ds_write AFTER compute (T14).
//  - Everything else unchanged from Round 4.

typedef __attribute__((ext_vector_type(8))) short short8;     // 8 bf16
typedef __attribute__((ext_vector_type(4))) float floatx4;
typedef __attribute__((ext_vector_type(8))) _Float16 half8;   // 8 fp16 = 16B

#define IN_CH 512
#define HID_CH 256
#define OUT_CH 64

static __device__ __forceinline__ unsigned short bf16_bits(float f) {
    __hip_bfloat16 b = __float2bfloat16(f);
    union { __hip_bfloat16 b; unsigned short u; } u2; u2.b = b; return u2.u;
}

typedef __attribute__((address_space(3))) unsigned int lds_u32;
typedef __attribute__((address_space(1))) const unsigned int glb_u32;

static __device__ __forceinline__ void gload16(const void* g, void* l) {
    __builtin_amdgcn_global_load_lds((glb_u32*)g, (lds_u32*)l, 16, 0, 0);
}

// meta[0]=1 iff edges are int32 words; meta[1]=1 iff float tensors are fp32
__global__ void k_probe(const int* __restrict__ e, long long ewords,
                        const unsigned short* __restrict__ xw,
                        int* __restrict__ meta) {
    if (blockIdx.x == 16) {
        int any = 0;
        long long half = ewords >> 1;
        long long step = half / 4096; if (step < 1) step = 1;
        for (long long i = threadIdx.x; i < 4096; i += blockDim.x) {
            long long idx = 2 * (i * step) + 1;
            if (idx < ewords) any |= e[idx];
        }
        if (any) atomicOr(&meta[0], 1);
    } else {
        const short8* x8 = (const short8*)xw;
        int bad = 0;
        for (int i = blockIdx.x * 256 + threadIdx.x; i < 8192; i += 4096) {
            short8 v = x8[i];
#pragma unroll
            for (int j = 0; j < 8; ++j) {
                unsigned short w = (unsigned short)v[j];
                if ((w & 0x7F80) == 0x7F80) bad = 1;  // bf16 inf/nan: impossible in N(0,1)
            }
        }
        if (bad) atomicOr(&meta[1], 1);
    }
}

__global__ void k_transpose(const void* __restrict__ w,
                            __hip_bfloat16* __restrict__ wt, int K, int N,
                            const int* __restrict__ meta) {
    int f32 = meta[1];
    int i = blockIdx.x * blockDim.x + threadIdx.x;
    if (i < K * N) {
        int k = i / N, n = i - k * N;
        __hip_bfloat16 v = f32 ? __float2bfloat16(((const float*)w)[i])
                               : ((const __hip_bfloat16*)w)[i];
        wt[n * K + k] = v;
    }
}

__global__ void k_count(const int* __restrict__ e, const int* __restrict__ meta,
                        int E, int* __restrict__ cnt, int* __restrict__ rank, int n) {
    int is32 = meta[0];
    int j = blockIdx.x * 256 + threadIdx.x;
    if (j < E) {
        long long idx = (long long)E + j;
        int d = is32 ? e[idx] : (int)((const long long*)e)[idx];
        if ((unsigned)d >= (unsigned)n) d = 0;
        rank[j] = atomicAdd(&cnt[d], 1);
    }
}

__global__ __launch_bounds__(1024) void k_scan1(const int* __restrict__ cnt,
                                                int* __restrict__ incl,
                                                int* __restrict__ bsum, int n) {
    __shared__ int s[1024];
    int i = blockIdx.x * 1024 + threadIdx.x;
    int v = (i < n) ? cnt[i] : 0;
    s[threadIdx.x] = v;
    __syncthreads();
    for (int off = 1; off < 1024; off <<= 1) {
        int t = (threadIdx.x >= off) ? s[threadIdx.x - off] : 0;
        __syncthreads();
        s[threadIdx.x] += t;
        __syncthreads();
    }
    incl[blockIdx.x * 1024 + threadIdx.x] = s[threadIdx.x];
    if (threadIdx.x == 1023) bsum[blockIdx.x] = s[1023];
}

__global__ void k_scan2(const int* __restrict__ bsum, int* __restrict__ boff, int nb) {
    if (blockIdx.x == 0 && threadIdx.x == 0) {
        int a = 0;
        for (int i = 0; i < nb; ++i) { boff[i] = a; a += bsum[i]; }
    }
}

__global__ void k_scan3(const int* __restrict__ incl, const int* __restrict__ cnt,
                        const int* __restrict__ boff, int* __restrict__ rowptr,
                        int n, int E) {
    int i = blockIdx.x * 256 + threadIdx.x;
    if (i < n) rowptr[i] = incl[i] - cnt[i] + boff[i >> 10];
    if (i == 0) rowptr[n] = E;
}

__global__ void k_dinv(const int* __restrict__ cnt, float* __restrict__ dinv, int n) {
    int i = blockIdx.x * 256 + threadIdx.x;
    if (i < n) dinv[i] = rsqrtf((float)cnt[i] + 1.0f);  // +1 self-loop
}

__global__ void k_fill(const int* __restrict__ e, const int* __restrict__ meta, int E,
                       const int* __restrict__ rowptr, const int* __restrict__ rank,
                       int* __restrict__ col, int n) {
    int is32 = meta[0];
    int j = blockIdx.x * 256 + threadIdx.x;
    if (j < E) {
        int s, d;
        if (is32) { s = e[j]; d = e[(long long)E + j]; }
        else {
            const long long* e64 = (const long long*)e;
            s = (int)e64[j]; d = (int)e64[(long long)E + j];
        }
        if ((unsigned)s >= (unsigned)n) s = 0;
        if ((unsigned)d >= (unsigned)n) d = 0;
        col[rowptr[d] + rank[j]] = s;
    }
}

// ---------- GEMM1: h1[M,256] = relu(x[M,512] @ w1 + b1), bf16 out ----------
// 64(M)x128(N) tile, BK=64, 4 waves each 32x64 (acc 2x4 of 16x16x32).
// 2-phase counted-vmcnt pipeline; LDS: A0 A1 (8KB each) B0 B1 (16KB each).
// XOR swizzle ((row&7)<<4) with pre-swizzled global source for gload paths.
__global__ __launch_bounds__(256, 4) void k_gemm1(
    const void* __restrict__ A, const __hip_bfloat16* __restrict__ Bt,
    const void* __restrict__ bias, __hip_bfloat16* __restrict__ C,
    int M, const int* __restrict__ meta)
{
    __shared__ __attribute__((aligned(16))) char lds[49152];
    const int f32 = meta[1];
    const int t = threadIdx.x;
    const int bm = blockIdx.x * 64, bn = blockIdx.y * 128;
    const int wave = t >> 6, lane = t & 63;
    const int wm = (wave & 1) * 32, wn = (wave >> 1) * 64;
    const int quad = lane >> 4, l16 = lane & 15;
    const int lrow = lane >> 3;                 // row within 8-row segment
    const int lcol = ((lane & 7) ^ lrow) * 8;   // pre-swizzled element offset

    floatx4 acc[2][4];
#pragma unroll
    for (int i = 0; i < 2; ++i)
#pragma unroll
        for (int j = 0; j < 4; ++j) acc[i][j] = {0.f, 0.f, 0.f, 0.f};

    const __hip_bfloat16* Ab = (const __hip_bfloat16*)A;
    const float* Af = (const float*)A;
    const int NT = IN_CH / 64;   // 8 K-steps

    // A rows this thread stages: segments s0=wave*2, s1=wave*2+1
    const int s0 = wave * 2, s1 = wave * 2 + 1;
    int gr0 = bm + 8 * s0 + lrow; if (gr0 >= M) gr0 = M - 1;
    int gr1 = bm + 8 * s1 + lrow; if (gr1 >= M) gr1 = M - 1;

#define ABUF(p) (lds + (p) * 8192)
#define BBUF(p) (lds + 16384 + (p) * 16384)

    if (f32) {
        float4 ar0a, ar0b, ar1a, ar1b;   // prefetched A regs for step t+1
        // ---- prologue: stage step 0 ----
        {
            const float* src0 = Af + (size_t)gr0 * IN_CH + lcol;
            const float* src1 = Af + (size_t)gr1 * IN_CH + lcol;
            float4 a0 = *(const float4*)src0, b0 = *(const float4*)(src0 + 4);
            float4 a1 = *(const float4*)src1, b1 = *(const float4*)(src1 + 4);
#pragma unroll
            for (int i = 0; i < 4; ++i)
                gload16(Bt + (size_t)(bn + 8 * (wave * 4 + i) + lrow) * IN_CH + lcol,
                        BBUF(0) + (wave * 4 + i) * 1024);
            union { short8 s8; unsigned short us[8]; } u;
            u.us[0] = bf16_bits(a0.x); u.us[1] = bf16_bits(a0.y);
            u.us[2] = bf16_bits(a0.z); u.us[3] = bf16_bits(a0.w);
            u.us[4] = bf16_bits(b0.x); u.us[5] = bf16_bits(b0.y);
            u.us[6] = bf16_bits(b0.z); u.us[7] = bf16_bits(b0.w);
            *(short8*)(ABUF(0) + s0 * 1024 + lane * 16) = u.s8;
            u.us[0] = bf16_bits(a1.x); u.us[1] = bf16_bits(a1.y);
            u.us[2] = bf16_bits(a1.z); u.us[3] = bf16_bits(a1.w);
            u.us[4] = bf16_bits(b1.x); u.us[5] = bf16_bits(b1.y);
            u.us[6] = bf16_bits(b1.z); u.us[7] = bf16_bits(b1.w);
            *(short8*)(ABUF(0) + s1 * 1024 + lane * 16) = u.s8;
        }
        for (int kt = 0; kt < NT; ++kt) {
            const int p = kt & 1;
            const int k0n = (kt + 1) * 64;
            if (kt + 1 < NT) {
                // issue A reg-loads first (older), then B gloads
                const float* src0 = Af + (size_t)gr0 * IN_CH + k0n + lcol;
                const float* src1 = Af + (size_t)gr1 * IN_CH + k0n + lcol;
                ar0a = *(const float4*)src0; ar0b = *(const float4*)(src0 + 4);
                ar1a = *(const float4*)src1; ar1b = *(const float4*)(src1 + 4);
#pragma unroll
                for (int i = 0; i < 4; ++i)
                    gload16(Bt + (size_t)(bn + 8 * (wave * 4 + i) + lrow) * IN_CH + k0n + lcol,
                            BBUF(p ^ 1) + (wave * 4 + i) * 1024);
                asm volatile("s_waitcnt vmcnt(8)" ::: "memory");
            } else {
                asm volatile("s_waitcnt vmcnt(0)" ::: "memory");
            }
            asm volatile("s_waitcnt lgkmcnt(0)" ::: "memory");
            __builtin_amdgcn_sched_barrier(0);
            __builtin_amdgcn_s_barrier();
#pragma unroll
            for (int kk = 0; kk < 64; kk += 32) {
                const int cb = kk * 2 + quad * 16;
                short8 af[2], bf[4];
#pragma unroll
                for (int i = 0; i < 2; ++i) {
                    int r = wm + i * 16 + l16;
                    af[i] = *(const short8*)(ABUF(p) + r * 128 + (cb ^ ((r & 7) << 4)));
                }
#pragma unroll
                for (int j = 0; j < 4; ++j) {
                    int r = wn + j * 16 + l16;
                    bf[j] = *(const short8*)(BBUF(p) + r * 128 + (cb ^ ((r & 7) << 4)));
                }
#pragma unroll
                for (int i = 0; i < 2; ++i)
#pragma unroll
                    for (int j = 0; j < 4; ++j)
                        acc[i][j] = __builtin_amdgcn_mfma_f32_16x16x32_bf16(af[i], bf[j], acc[i][j], 0, 0, 0);
            }
            if (kt + 1 < NT) {
                // cvt + ds_write A(t+1) -> other buffer (compiler waits vmcnt(4))
                union { short8 s8; unsigned short us[8]; } u;
                u.us[0] = bf16_bits(ar0a.x); u.us[1] = bf16_bits(ar0a.y);
                u.us[2] = bf16_bits(ar0a.z); u.us[3] = bf16_bits(ar0a.w);
                u.us[4] = bf16_bits(ar0b.x); u.us[5] = bf16_bits(ar0b.y);
                u.us[6] = bf16_bits(ar0b.z); u.us[7] = bf16_bits(ar0b.w);
                *(short8*)(ABUF(p ^ 1) + s0 * 1024 + lane * 16) = u.s8;
                u.us[0] = bf16_bits(ar1a.x); u.us[1] = bf16_bits(ar1a.y);
                u.us[2] = bf16_bits(ar1a.z); u.us[3] = bf16_bits(ar1a.w);
                u.us[4] = bf16_bits(ar1b.x); u.us[5] = bf16_bits(ar1b.y);
                u.us[6] = bf16_bits(ar1b.z); u.us[7] = bf16_bits(ar1b.w);
                *(short8*)(ABUF(p ^ 1) + s1 * 1024 + lane * 16) = u.s8;
            }
            __builtin_amdgcn_s_barrier();
        }
    } else {
        // bf16 x: all-gload pipeline (A 2 + B 4 = 6 insts per stage)
#pragma unroll
        for (int i = 0; i < 4; ++i)
            gload16(Bt + (size_t)(bn + 8 * (wave * 4 + i) + lrow) * IN_CH + lcol,
                    BBUF(0) + (wave * 4 + i) * 1024);
        gload16(Ab + (size_t)gr0 * IN_CH + lcol, ABUF(0) + s0 * 1024);
        gload16(Ab + (size_t)gr1 * IN_CH + lcol, ABUF(0) + s1 * 1024);
        for (int kt = 0; kt < NT; ++kt) {
            const int p = kt & 1;
            const int k0n = (kt + 1) * 64;
            if (kt + 1 < NT) {
#pragma unroll
                for (int i = 0; i < 4; ++i)
                    gload16(Bt + (size_t)(bn + 8 * (wave * 4 + i) + lrow) * IN_CH + k0n + lcol,
                            BBUF(p ^ 1) + (wave * 4 + i) * 1024);
                gload16(Ab + (size_t)gr0 * IN_CH + k0n + lcol, ABUF(p ^ 1) + s0 * 1024);
                gload16(Ab + (size_t)gr1 * IN_CH + k0n + lcol, ABUF(p ^ 1) + s1 * 1024);
                asm volatile("s_waitcnt vmcnt(6)" ::: "memory");
            } else {
                asm volatile("s_waitcnt vmcnt(0)" ::: "memory");
            }
            asm volatile("s_waitcnt lgkmcnt(0)" ::: "memory");
            __builtin_amdgcn_sched_barrier(0);
            __builtin_amdgcn_s_barrier();
#pragma unroll
            for (int kk = 0; kk < 64; kk += 32) {
                const int cb = kk * 2 + quad * 16;
                short8 af[2], bf[4];
#pragma unroll
                for (int i = 0; i < 2; ++i) {
                    int r = wm + i * 16 + l16;
                    af[i] = *(const short8*)(ABUF(p) + r * 128 + (cb ^ ((r & 7) << 4)));
                }
#pragma unroll
                for (int j = 0; j < 4; ++j) {
                    int r = wn + j * 16 + l16;
                    bf[j] = *(const short8*)(BBUF(p) + r * 128 + (cb ^ ((r & 7) << 4)));
                }
#pragma unroll
                for (int i = 0; i < 2; ++i)
#pragma unroll
                    for (int j = 0; j < 4; ++j)
                        acc[i][j] = __builtin_amdgcn_mfma_f32_16x16x32_bf16(af[i], bf[j], acc[i][j], 0, 0, 0);
            }
            __builtin_amdgcn_s_barrier();
        }
    }
#undef ABUF
#undef BBUF

#pragma unroll
    for (int i = 0; i < 2; ++i)
#pragma unroll
        for (int j = 0; j < 4; ++j) {
            int nn = bn + wn + j * 16 + l16;
            float bv = f32 ? ((const float*)bias)[nn]
                           : __bfloat162float(((const __hip_bfloat16*)bias)[nn]);
#pragma unroll
            for (int r = 0; r < 4; ++r) {
                int m = bm + wm + i * 16 + quad * 4 + r;
                if (m < M)
                    C[(size_t)m * HID_CH + nn] = __float2bfloat16(fmaxf(acc[i][j][r] + bv, 0.f));
            }
        }
}

// ---------- GEMM2: h0[M,64] = h1 @ w2 + b2; emit h0 (fp16) and g0=dinv*h0 ----------
__global__ __launch_bounds__(256) void k_gemm2(
    const __hip_bfloat16* __restrict__ A, const __hip_bfloat16* __restrict__ Bt,
    const void* __restrict__ bias, const float* __restrict__ dinv,
    _Float16* __restrict__ h0h, _Float16* __restrict__ g0,
    int M, const int* __restrict__ meta)
{
    __shared__ __attribute__((aligned(16))) short As[64 * 72];
    __shared__ __attribute__((aligned(16))) short Bs[64 * 72];
    const int f32 = meta[1];
    const int t = threadIdx.x;
    const int bm = blockIdx.x * 64;
    const int wave = t >> 6, lane = t & 63;
    const int wm = (wave >> 1) * 32, wn = (wave & 1) * 32;
    const int quad = lane >> 4, l16 = lane & 15;

    floatx4 acc[2][2];
#pragma unroll
    for (int i = 0; i < 2; ++i)
#pragma unroll
        for (int j = 0; j < 2; ++j) acc[i][j] = {0.f, 0.f, 0.f, 0.f};

    for (int k0 = 0; k0 < HID_CH; k0 += 64) {
        __syncthreads();
        for (int ch = t; ch < 1024; ch += 256) {
            int row = (ch & 511) >> 3, off = (ch & 7) * 8;
            if (ch < 512) {
                uint4 av = {0u, 0u, 0u, 0u};
                int gr = bm + row;
                if (gr < M)
                    av = *(const uint4*)((const char*)A + ((size_t)gr * HID_CH + k0 + off) * 2);
                *(uint4*)((char*)As + row * 144 + off * 2) = av;
            } else {
                uint4 bv = *(const uint4*)((const char*)Bt + ((size_t)row * HID_CH + k0 + off) * 2);
                *(uint4*)((char*)Bs + row * 144 + off * 2) = bv;
            }
        }
        __syncthreads();
#pragma unroll
        for (int kk = 0; kk < 64; kk += 32) {
            short8 af[2], bf[2];
#pragma unroll
            for (int i = 0; i < 2; ++i)
                af[i] = *(const short8*)((const char*)As + (wm + i * 16 + l16) * 144 + (kk + quad * 8) * 2);
#pragma unroll
            for (int j = 0; j < 2; ++j)
                bf[j] = *(const short8*)((const char*)Bs + (wn + j * 16 + l16) * 144 + (kk + quad * 8) * 2);
#pragma unroll
            for (int i = 0; i < 2; ++i)
#pragma unroll
                for (int j = 0; j < 2; ++j)
                    acc[i][j] = __builtin_amdgcn_mfma_f32_16x16x32_bf16(af[i], bf[j], acc[i][j], 0, 0, 0);
        }
    }

#pragma unroll
    for (int i = 0; i < 2; ++i) {
#pragma unroll
        for (int j = 0; j < 2; ++j) {
            int nn = wn + j * 16 + l16;
            float bv = f32 ? ((const float*)bias)[nn]
                           : __bfloat162float(((const __hip_bfloat16*)bias)[nn]);
#pragma unroll
            for (int r = 0; r < 4; ++r) {
                int m = bm + wm + i * 16 + quad * 4 + r;
                if (m < M) {
                    float v = acc[i][j][r] + bv;
                    float dv = dinv[m];
                    h0h[(size_t)m * OUT_CH + nn] = (_Float16)v;
                    g0[(size_t)m * OUT_CH + nn] = (_Float16)(dv * v);
                }
            }
        }
    }
}

// ---------- propagation in g-space ----------
// S_i = g[i] + sum_{e in row i} g[col[e]]
// intermediate: g_out[i] = 0.9*dinv^2*S + 0.1*dinv*h0
// final:        out[i]   = 0.9*dinv*S   + 0.1*h0
// 8 lanes per node (16B fp16 each), 32 nodes per 256-thread block.
template<int FINAL>
__global__ __launch_bounds__(256) void k_prop(
    const _Float16* __restrict__ g, const _Float16* __restrict__ h0h,
    const int* __restrict__ rowptr, const int* __restrict__ col,
    const float* __restrict__ dinv,
    _Float16* __restrict__ gout, void* __restrict__ outfinal, int n,
    const int* __restrict__ meta)
{
    int gid = blockIdx.x * 32 + (threadIdx.x >> 3);
    if (gid >= n) return;
    int lane = threadIdx.x & 7;
    const half8* g8 = (const half8*)g;

    half8 sv = g8[(size_t)gid * 8 + lane];
    float acc[8];
#pragma unroll
    for (int i = 0; i < 8; ++i) acc[i] = (float)sv[i];

    int e0 = rowptr[gid], e1 = rowptr[gid + 1];
    int e = e0;
    for (; e + 8 <= e1; e += 8) {
        int c[8];
#pragma unroll
        for (int u = 0; u < 8; ++u) c[u] = col[e + u];
        half8 v[8];
#pragma unroll
        for (int u = 0; u < 8; ++u) v[u] = g8[(size_t)c[u] * 8 + lane];
#pragma unroll
        for (int u = 0; u < 8; ++u)
#pragma unroll
            for (int i = 0; i < 8; ++i) acc[i] += (float)v[u][i];
    }
    for (; e + 4 <= e1; e += 4) {
        int c0 = col[e], c1 = col[e + 1], c2 = col[e + 2], c3 = col[e + 3];
        half8 v0 = g8[(size_t)c0 * 8 + lane];
        half8 v1 = g8[(size_t)c1 * 8 + lane];
        half8 v2 = g8[(size_t)c2 * 8 + lane];
        half8 v3 = g8[(size_t)c3 * 8 + lane];
#pragma unroll
        for (int i = 0; i < 8; ++i)
            acc[i] += ((float)v0[i] + (float)v1[i]) + ((float)v2[i] + (float)v3[i]);
    }
    for (; e < e1; ++e) {
        half8 v = g8[(size_t)col[e] * 8 + lane];
#pragma unroll
        for (int i = 0; i < 8; ++i) acc[i] += (float)v[i];
    }

    float dv = dinv[gid];
    half8 z = ((const half8*)h0h)[(size_t)gid * 8 + lane];

    if (FINAL) {
        float o[8];
#pragma unroll
        for (int i = 0; i < 8; ++i) o[i] = 0.9f * dv * acc[i] + 0.1f * (float)z[i];
        if (meta[1]) {
            float* of = (float*)outfinal + (size_t)gid * OUT_CH + lane * 8;
            float4 a = {o[0], o[1], o[2], o[3]}, b = {o[4], o[5], o[6], o[7]};
            *(float4*)of = a; *(float4*)(of + 4) = b;
        } else {
            struct alignas(16) BF8 { unsigned short v[8]; } ob;
#pragma unroll
            for (int i = 0; i < 8; ++i) ob.v[i] = bf16_bits(o[i]);
            *(BF8*)((unsigned short*)outfinal + (size_t)gid * OUT_CH + lane * 8) = ob;
        }
    } else {
        float w2v = 0.9f * dv * dv, w1v = 0.1f * dv;
        half8 o;
#pragma unroll
        for (int i = 0; i < 8; ++i) o[i] = (_Float16)(w2v * acc[i] + w1v * (float)z[i]);
        ((half8*)gout)[(size_t)gid * 8 + lane] = o;
    }
}

extern "C" void kernel_launch(void* const* d_in, const int* in_sizes, int n_in,
                              void* d_out, int out_size, void* d_ws, size_t ws_size,
                              hipStream_t stream) {
    const void* x    = d_in[0];
    const int* edges = (const int*)d_in[1];
    const void* w1   = d_in[2];
    const void* b1   = d_in[3];
    const void* w2   = d_in[4];
    const void* b2   = d_in[5];

    const int N = in_sizes[0] / IN_CH;   // 100000
    const int E = in_sizes[1] / 2;       // 1600000
    const int NB = (N + 1023) / 1024;

    size_t off = 0;
    auto carve = [&](size_t bytes) -> void* {
        void* r = (char*)d_ws + off;
        off += (bytes + 255) & ~(size_t)255;
        return r;
    };
    __hip_bfloat16* h1  = (__hip_bfloat16*)carve((size_t)N * HID_CH * 2);
    _Float16* h0h       = (_Float16*)carve((size_t)N * OUT_CH * 2);
    _Float16* gA        = (_Float16*)carve((size_t)N * OUT_CH * 2);
    _Float16* gB        = (_Float16*)carve((size_t)N * OUT_CH * 2);
    __hip_bfloat16* w1t = (__hip_bfloat16*)carve((size_t)IN_CH * HID_CH * 2);
    __hip_bfloat16* w2t = (__hip_bfloat16*)carve((size_t)HID_CH * OUT_CH * 2);
    int* cnt            = (int*)carve((size_t)N * 4);
    int* incl           = (int*)carve((size_t)NB * 1024 * 4);
    int* bsum           = (int*)carve(1024 * 4);
    int* boff           = (int*)carve(1024 * 4);
    int* rowptr         = (int*)carve((size_t)(N + 1) * 4);
    float* dinv         = (float*)carve((size_t)N * 4);
    int* col            = (int*)carve((size_t)E * 4);
    int* meta           = (int*)carve(256);
    if (off > ws_size) return;

    // rank[] (E ints) aliases h1: written by k_count, consumed by k_fill,
    // both strictly before k_gemm1 writes h1 (single stream).
    int* rank = (int*)h1;

    hipMemsetAsync(cnt, 0, (size_t)N * 4, stream);
    hipMemsetAsync(meta, 0, 8, stream);

    k_probe<<<17, 256, 0, stream>>>(edges, (long long)2 * E,
                                    (const unsigned short*)x, meta);

    k_transpose<<<(IN_CH * HID_CH + 255) / 256, 256, 0, stream>>>(w1, w1t, IN_CH, HID_CH, meta);
    k_transpose<<<(HID_CH * OUT_CH + 255) / 256, 256, 0, stream>>>(w2, w2t, HID_CH, OUT_CH, meta);

    // CSR build (dinv needed by k_gemm2 epilogue)
    const int EB = (E + 255) / 256;
    k_count<<<EB, 256, 0, stream>>>(edges, meta, E, cnt, rank, N);
    k_scan1<<<NB, 1024, 0, stream>>>(cnt, incl, bsum, N);
    k_scan2<<<1, 64, 0, stream>>>(bsum, boff, NB);
    k_scan3<<<(N + 255) / 256, 256, 0, stream>>>(incl, cnt, boff, rowptr, N, E);
    k_dinv<<<(N + 255) / 256, 256, 0, stream>>>(cnt, dinv, N);
    k_fill<<<EB, 256, 0, stream>>>(edges, meta, E, rowptr, rank, col, N);

    // MLP
    dim3 g1((N + 63) / 64, 2);
    k_gemm1<<<g1, 256, 0, stream>>>(x, w1t, b1, h1, N, meta);
    const int MB = (N + 63) / 64;
    k_gemm2<<<MB, 256, 0, stream>>>(h1, w2t, b2, dinv, h0h, gA, N, meta);

    // 10 propagation rounds in g-space; last writes d_out
    const int PB = (N + 31) / 32;
    const _Float16* cur = gA;
    _Float16* nxt = gB;
    for (int it = 0; it < 10; ++it) {
        if (it < 9) {
            k_prop<0><<<PB, 256, 0, stream>>>(cur, h0h, rowptr, col, dinv, nxt, nullptr, N, meta);
            const _Float16* tmp = cur; cur = nxt; nxt = (_Float16*)tmp;
        } else {
            k_prop<1><<<PB, 256, 0, stream>>>(cur, h0h, rowptr, col, dinv, nullptr, d_out, N, meta);
        }
    }
}

// Round 7
// 815.057 us; speedup vs baseline: 1.0282x; 1.0282x over previous
//
#include <hip/hip_runtime.h>
#include <hip/hip_bf16.h>

// APPNP: h = MLP(x); h_{t+1} = 0.9 * (D^-1/2 (A+I) D^-1/2) h_t + 0.1 * h0, K=10
// Round 7 (this session):
//  - GEMM1 retiled to BM=128 x BN=256 (FULL N, no y-split): aggregate VMEM
//    demand drops 800 MB -> 405 MB (R3/R4/R6 all showed ~6 TB/s achieved
//    VMEM ceiling regardless of sync structure -> traffic is the lever).
//    1024 threads / 16 waves (4M x 4N), wave tile 32x64 (acc[2][4] = 32 regs,
//    ~90 total -> 4 waves/SIMD via __launch_bounds__(1024,4)); 48 KB LDS,
//    single-buffered, plain __syncthreads (counted-vmcnt gained nothing in R6).
//  - Everything else unchanged from Round 6.

typedef __attribute__((ext_vector_type(8))) short short8;     // 8 bf16
typedef __attribute__((ext_vector_type(4))) float floatx4;
typedef __attribute__((ext_vector_type(8))) _Float16 half8;   // 8 fp16 = 16B

#define IN_CH 512
#define HID_CH 256
#define OUT_CH 64

static __device__ __forceinline__ unsigned short bf16_bits(float f) {
    __hip_bfloat16 b = __float2bfloat16(f);
    union { __hip_bfloat16 b; unsigned short u; } u2; u2.b = b; return u2.u;
}

typedef __attribute__((address_space(3))) unsigned int lds_u32;
typedef __attribute__((address_space(1))) const unsigned int glb_u32;

static __device__ __forceinline__ void gload16(const void* g, void* l) {
    __builtin_amdgcn_global_load_lds((glb_u32*)g, (lds_u32*)l, 16, 0, 0);
}

// meta[0]=1 iff edges are int32 words; meta[1]=1 iff float tensors are fp32
__global__ void k_probe(const int* __restrict__ e, long long ewords,
                        const unsigned short* __restrict__ xw,
                        int* __restrict__ meta) {
    if (blockIdx.x == 16) {
        int any = 0;
        long long half = ewords >> 1;
        long long step = half / 4096; if (step < 1) step = 1;
        for (long long i = threadIdx.x; i < 4096; i += blockDim.x) {
            long long idx = 2 * (i * step) + 1;
            if (idx < ewords) any |= e[idx];
        }
        if (any) atomicOr(&meta[0], 1);
    } else {
        const short8* x8 = (const short8*)xw;
        int bad = 0;
        for (int i = blockIdx.x * 256 + threadIdx.x; i < 8192; i += 4096) {
            short8 v = x8[i];
#pragma unroll
            for (int j = 0; j < 8; ++j) {
                unsigned short w = (unsigned short)v[j];
                if ((w & 0x7F80) == 0x7F80) bad = 1;  // bf16 inf/nan: impossible in N(0,1)
            }
        }
        if (bad) atomicOr(&meta[1], 1);
    }
}

__global__ void k_transpose(const void* __restrict__ w,
                            __hip_bfloat16* __restrict__ wt, int K, int N,
                            const int* __restrict__ meta) {
    int f32 = meta[1];
    int i = blockIdx.x * blockDim.x + threadIdx.x;
    if (i < K * N) {
        int k = i / N, n = i - k * N;
        __hip_bfloat16 v = f32 ? __float2bfloat16(((const float*)w)[i])
                               : ((const __hip_bfloat16*)w)[i];
        wt[n * K + k] = v;
    }
}

__global__ void k_count(const int* __restrict__ e, const int* __restrict__ meta,
                        int E, int* __restrict__ cnt, int* __restrict__ rank, int n) {
    int is32 = meta[0];
    int j = blockIdx.x * 256 + threadIdx.x;
    if (j < E) {
        long long idx = (long long)E + j;
        int d = is32 ? e[idx] : (int)((const long long*)e)[idx];
        if ((unsigned)d >= (unsigned)n) d = 0;
        rank[j] = atomicAdd(&cnt[d], 1);
    }
}

__global__ __launch_bounds__(1024) void k_scan1(const int* __restrict__ cnt,
                                                int* __restrict__ incl,
                                                int* __restrict__ bsum, int n) {
    __shared__ int s[1024];
    int i = blockIdx.x * 1024 + threadIdx.x;
    int v = (i < n) ? cnt[i] : 0;
    s[threadIdx.x] = v;
    __syncthreads();
    for (int off = 1; off < 1024; off <<= 1) {
        int t = (threadIdx.x >= off) ? s[threadIdx.x - off] : 0;
        __syncthreads();
        s[threadIdx.x] += t;
        __syncthreads();
    }
    incl[blockIdx.x * 1024 + threadIdx.x] = s[threadIdx.x];
    if (threadIdx.x == 1023) bsum[blockIdx.x] = s[1023];
}

__global__ void k_scan2(const int* __restrict__ bsum, int* __restrict__ boff, int nb) {
    if (blockIdx.x == 0 && threadIdx.x == 0) {
        int a = 0;
        for (int i = 0; i < nb; ++i) { boff[i] = a; a += bsum[i]; }
    }
}

__global__ void k_scan3(const int* __restrict__ incl, const int* __restrict__ cnt,
                        const int* __restrict__ boff, int* __restrict__ rowptr,
                        int n, int E) {
    int i = blockIdx.x * 256 + threadIdx.x;
    if (i < n) rowptr[i] = incl[i] - cnt[i] + boff[i >> 10];
    if (i == 0) rowptr[n] = E;
}

__global__ void k_dinv(const int* __restrict__ cnt, float* __restrict__ dinv, int n) {
    int i = blockIdx.x * 256 + threadIdx.x;
    if (i < n) dinv[i] = rsqrtf((float)cnt[i] + 1.0f);  // +1 self-loop
}

__global__ void k_fill(const int* __restrict__ e, const int* __restrict__ meta, int E,
                       const int* __restrict__ rowptr, const int* __restrict__ rank,
                       int* __restrict__ col, int n) {
    int is32 = meta[0];
    int j = blockIdx.x * 256 + threadIdx.x;
    if (j < E) {
        int s, d;
        if (is32) { s = e[j]; d = e[(long long)E + j]; }
        else {
            const long long* e64 = (const long long*)e;
            s = (int)e64[j]; d = (int)e64[(long long)E + j];
        }
        if ((unsigned)s >= (unsigned)n) s = 0;
        if ((unsigned)d >= (unsigned)n) d = 0;
        col[rowptr[d] + rank[j]] = s;
    }
}

// ---------- GEMM1: h1[M,256] = relu(x[M,512] @ w1 + b1), bf16 out ----------
// BM=128, BN=256 (full N). 1024 threads = 16 waves as 4Mx4N, wave tile 32x64
// (acc 2x4 of 16x16x32). LDS: A[128][64] 16KB + B[256][64] 32KB, XOR-swizzled
// ((row&7)<<4) with pre-swizzled global source; B (and bf16-A) via
// global_load_lds w16; fp32-A via float4 x2 + cvt + contiguous ds_write.
// VMEM demand: A 256KB + B 256KB per 128-row strip -> 405 MB total (was 800).
__global__ __launch_bounds__(1024, 4) void k_gemm1(
    const void* __restrict__ A, const __hip_bfloat16* __restrict__ Bt,
    const void* __restrict__ bias, __hip_bfloat16* __restrict__ C,
    int M, const int* __restrict__ meta)
{
    __shared__ __attribute__((aligned(16))) char lds[49152];
    const int f32 = meta[1];
    const int t = threadIdx.x;
    const int bm = blockIdx.x * 128;
    const int wave = t >> 6, lane = t & 63;
    const int wm = (wave & 3) * 32, wn = (wave >> 2) * 64;
    const int quad = lane >> 4, l16 = lane & 15;
    const int lrow = lane >> 3;                 // row within 8-row segment
    const int lcol = ((lane & 7) ^ lrow) * 8;   // pre-swizzled element offset

    floatx4 acc[2][4];
#pragma unroll
    for (int i = 0; i < 2; ++i)
#pragma unroll
        for (int j = 0; j < 4; ++j) acc[i][j] = {0.f, 0.f, 0.f, 0.f};

    const __hip_bfloat16* Ab = (const __hip_bfloat16*)A;
    const float* Af = (const float*)A;

#define ABASE (lds)
#define BBASE (lds + 16384)

    // A: 16 segments of 8 rows, wave stages seg s=wave.
    // B: 32 segments of 8 n-rows, wave stages segs wave*2, wave*2+1.
    int gr = bm + 8 * wave + lrow; if (gr >= M) gr = M - 1;

    for (int k0 = 0; k0 < IN_CH; k0 += 64) {
        __syncthreads();
#pragma unroll
        for (int i = 0; i < 2; ++i) {
            int s = wave * 2 + i;
            gload16(Bt + (size_t)(8 * s + lrow) * IN_CH + k0 + lcol,
                    BBASE + s * 1024);
        }
        if (f32) {
            const float* src = Af + (size_t)gr * IN_CH + k0 + lcol;
            float4 a = *(const float4*)src;
            float4 b = *(const float4*)(src + 4);
            union { short8 s8; unsigned short us[8]; } u;
            u.us[0] = bf16_bits(a.x); u.us[1] = bf16_bits(a.y);
            u.us[2] = bf16_bits(a.z); u.us[3] = bf16_bits(a.w);
            u.us[4] = bf16_bits(b.x); u.us[5] = bf16_bits(b.y);
            u.us[6] = bf16_bits(b.z); u.us[7] = bf16_bits(b.w);
            *(short8*)(ABASE + wave * 1024 + lane * 16) = u.s8;
        } else {
            gload16(Ab + (size_t)gr * IN_CH + k0 + lcol, ABASE + wave * 1024);
        }
        __syncthreads();
#pragma unroll
        for (int kk = 0; kk < 64; kk += 32) {
            const int cb = kk * 2 + quad * 16;
            short8 af[2], bf[4];
#pragma unroll
            for (int i = 0; i < 2; ++i) {
                int r = wm + i * 16 + l16;
                af[i] = *(const short8*)(ABASE + r * 128 + (cb ^ ((r & 7) << 4)));
            }
#pragma unroll
            for (int j = 0; j < 4; ++j) {
                int r = wn + j * 16 + l16;
                bf[j] = *(const short8*)(BBASE + r * 128 + (cb ^ ((r & 7) << 4)));
            }
#pragma unroll
            for (int i = 0; i < 2; ++i)
#pragma unroll
                for (int j = 0; j < 4; ++j)
                    acc[i][j] = __builtin_amdgcn_mfma_f32_16x16x32_bf16(af[i], bf[j], acc[i][j], 0, 0, 0);
        }
    }
#undef ABASE
#undef BBASE

#pragma unroll
    for (int i = 0; i < 2; ++i)
#pragma unroll
        for (int j = 0; j < 4; ++j) {
            int nn = wn + j * 16 + l16;
            float bv = f32 ? ((const float*)bias)[nn]
                           : __bfloat162float(((const __hip_bfloat16*)bias)[nn]);
#pragma unroll
            for (int r = 0; r < 4; ++r) {
                int m = bm + wm + i * 16 + quad * 4 + r;
                if (m < M)
                    C[(size_t)m * HID_CH + nn] = __float2bfloat16(fmaxf(acc[i][j][r] + bv, 0.f));
            }
        }
}

// ---------- GEMM2: h0[M,64] = h1 @ w2 + b2; emit h0 (fp16) and g0=dinv*h0 ----------
__global__ __launch_bounds__(256) void k_gemm2(
    const __hip_bfloat16* __restrict__ A, const __hip_bfloat16* __restrict__ Bt,
    const void* __restrict__ bias, const float* __restrict__ dinv,
    _Float16* __restrict__ h0h, _Float16* __restrict__ g0,
    int M, const int* __restrict__ meta)
{
    __shared__ __attribute__((aligned(16))) short As[64 * 72];
    __shared__ __attribute__((aligned(16))) short Bs[64 * 72];
    const int f32 = meta[1];
    const int t = threadIdx.x;
    const int bm = blockIdx.x * 64;
    const int wave = t >> 6, lane = t & 63;
    const int wm = (wave >> 1) * 32, wn = (wave & 1) * 32;
    const int quad = lane >> 4, l16 = lane & 15;

    floatx4 acc[2][2];
#pragma unroll
    for (int i = 0; i < 2; ++i)
#pragma unroll
        for (int j = 0; j < 2; ++j) acc[i][j] = {0.f, 0.f, 0.f, 0.f};

    for (int k0 = 0; k0 < HID_CH; k0 += 64) {
        __syncthreads();
        for (int ch = t; ch < 1024; ch += 256) {
            int row = (ch & 511) >> 3, off = (ch & 7) * 8;
            if (ch < 512) {
                uint4 av = {0u, 0u, 0u, 0u};
                int gr = bm + row;
                if (gr < M)
                    av = *(const uint4*)((const char*)A + ((size_t)gr * HID_CH + k0 + off) * 2);
                *(uint4*)((char*)As + row * 144 + off * 2) = av;
            } else {
                uint4 bv = *(const uint4*)((const char*)Bt + ((size_t)row * HID_CH + k0 + off) * 2);
                *(uint4*)((char*)Bs + row * 144 + off * 2) = bv;
            }
        }
        __syncthreads();
#pragma unroll
        for (int kk = 0; kk < 64; kk += 32) {
            short8 af[2], bf[2];
#pragma unroll
            for (int i = 0; i < 2; ++i)
                af[i] = *(const short8*)((const char*)As + (wm + i * 16 + l16) * 144 + (kk + quad * 8) * 2);
#pragma unroll
            for (int j = 0; j < 2; ++j)
                bf[j] = *(const short8*)((const char*)Bs + (wn + j * 16 + l16) * 144 + (kk + quad * 8) * 2);
#pragma unroll
            for (int i = 0; i < 2; ++i)
#pragma unroll
                for (int j = 0; j < 2; ++j)
                    acc[i][j] = __builtin_amdgcn_mfma_f32_16x16x32_bf16(af[i], bf[j], acc[i][j], 0, 0, 0);
        }
    }

#pragma unroll
    for (int i = 0; i < 2; ++i) {
#pragma unroll
        for (int j = 0; j < 2; ++j) {
            int nn = wn + j * 16 + l16;
            float bv = f32 ? ((const float*)bias)[nn]
                           : __bfloat162float(((const __hip_bfloat16*)bias)[nn]);
#pragma unroll
            for (int r = 0; r < 4; ++r) {
                int m = bm + wm + i * 16 + quad * 4 + r;
                if (m < M) {
                    float v = acc[i][j][r] + bv;
                    float dv = dinv[m];
                    h0h[(size_t)m * OUT_CH + nn] = (_Float16)v;
                    g0[(size_t)m * OUT_CH + nn] = (_Float16)(dv * v);
                }
            }
        }
    }
}

// ---------- propagation in g-space ----------
// S_i = g[i] + sum_{e in row i} g[col[e]]
// intermediate: g_out[i] = 0.9*dinv^2*S + 0.1*dinv*h0
// final:        out[i]   = 0.9*dinv*S   + 0.1*h0
// 8 lanes per node (16B fp16 each), 32 nodes per 256-thread block.
template<int FINAL>
__global__ __launch_bounds__(256) void k_prop(
    const _Float16* __restrict__ g, const _Float16* __restrict__ h0h,
    const int* __restrict__ rowptr, const int* __restrict__ col,
    const float* __restrict__ dinv,
    _Float16* __restrict__ gout, void* __restrict__ outfinal, int n,
    const int* __restrict__ meta)
{
    int gid = blockIdx.x * 32 + (threadIdx.x >> 3);
    if (gid >= n) return;
    int lane = threadIdx.x & 7;
    const half8* g8 = (const half8*)g;

    half8 sv = g8[(size_t)gid * 8 + lane];
    float acc[8];
#pragma unroll
    for (int i = 0; i < 8; ++i) acc[i] = (float)sv[i];

    int e0 = rowptr[gid], e1 = rowptr[gid + 1];
    int e = e0;
    for (; e + 8 <= e1; e += 8) {
        int c[8];
#pragma unroll
        for (int u = 0; u < 8; ++u) c[u] = col[e + u];
        half8 v[8];
#pragma unroll
        for (int u = 0; u < 8; ++u) v[u] = g8[(size_t)c[u] * 8 + lane];
#pragma unroll
        for (int u = 0; u < 8; ++u)
#pragma unroll
            for (int i = 0; i < 8; ++i) acc[i] += (float)v[u][i];
    }
    for (; e + 4 <= e1; e += 4) {
        int c0 = col[e], c1 = col[e + 1], c2 = col[e + 2], c3 = col[e + 3];
        half8 v0 = g8[(size_t)c0 * 8 + lane];
        half8 v1 = g8[(size_t)c1 * 8 + lane];
        half8 v2 = g8[(size_t)c2 * 8 + lane];
        half8 v3 = g8[(size_t)c3 * 8 + lane];
#pragma unroll
        for (int i = 0; i < 8; ++i)
            acc[i] += ((float)v0[i] + (float)v1[i]) + ((float)v2[i] + (float)v3[i]);
    }
    for (; e < e1; ++e) {
        half8 v = g8[(size_t)col[e] * 8 + lane];
#pragma unroll
        for (int i = 0; i < 8; ++i) acc[i] += (float)v[i];
    }

    float dv = dinv[gid];
    half8 z = ((const half8*)h0h)[(size_t)gid * 8 + lane];

    if (FINAL) {
        float o[8];
#pragma unroll
        for (int i = 0; i < 8; ++i) o[i] = 0.9f * dv * acc[i] + 0.1f * (float)z[i];
        if (meta[1]) {
            float* of = (float*)outfinal + (size_t)gid * OUT_CH + lane * 8;
            float4 a = {o[0], o[1], o[2], o[3]}, b = {o[4], o[5], o[6], o[7]};
            *(float4*)of = a; *(float4*)(of + 4) = b;
        } else {
            struct alignas(16) BF8 { unsigned short v[8]; } ob;
#pragma unroll
            for (int i = 0; i < 8; ++i) ob.v[i] = bf16_bits(o[i]);
            *(BF8*)((unsigned short*)outfinal + (size_t)gid * OUT_CH + lane * 8) = ob;
        }
    } else {
        float w2v = 0.9f * dv * dv, w1v = 0.1f * dv;
        half8 o;
#pragma unroll
        for (int i = 0; i < 8; ++i) o[i] = (_Float16)(w2v * acc[i] + w1v * (float)z[i]);
        ((half8*)gout)[(size_t)gid * 8 + lane] = o;
    }
}

extern "C" void kernel_launch(void* const* d_in, const int* in_sizes, int n_in,
                              void* d_out, int out_size, void* d_ws, size_t ws_size,
                              hipStream_t stream) {
    const void* x    = d_in[0];
    const int* edges = (const int*)d_in[1];
    const void* w1   = d_in[2];
    const void* b1   = d_in[3];
    const void* w2   = d_in[4];
    const void* b2   = d_in[5];

    const int N = in_sizes[0] / IN_CH;   // 100000
    const int E = in_sizes[1] / 2;       // 1600000
    const int NB = (N + 1023) / 1024;

    size_t off = 0;
    auto carve = [&](size_t bytes) -> void* {
        void* r = (char*)d_ws + off;
        off += (bytes + 255) & ~(size_t)255;
        return r;
    };
    __hip_bfloat16* h1  = (__hip_bfloat16*)carve((size_t)N * HID_CH * 2);
    _Float16* h0h       = (_Float16*)carve((size_t)N * OUT_CH * 2);
    _Float16* gA        = (_Float16*)carve((size_t)N * OUT_CH * 2);
    _Float16* gB        = (_Float16*)carve((size_t)N * OUT_CH * 2);
    __hip_bfloat16* w1t = (__hip_bfloat16*)carve((size_t)IN_CH * HID_CH * 2);
    __hip_bfloat16* w2t = (__hip_bfloat16*)carve((size_t)HID_CH * OUT_CH * 2);
    int* cnt            = (int*)carve((size_t)N * 4);
    int* incl           = (int*)carve((size_t)NB * 1024 * 4);
    int* bsum           = (int*)carve(1024 * 4);
    int* boff           = (int*)carve(1024 * 4);
    int* rowptr         = (int*)carve((size_t)(N + 1) * 4);
    float* dinv         = (float*)carve((size_t)N * 4);
    int* col            = (int*)carve((size_t)E * 4);
    int* meta           = (int*)carve(256);
    if (off > ws_size) return;

    // rank[] (E ints) aliases h1: written by k_count, consumed by k_fill,
    // both strictly before k_gemm1 writes h1 (single stream).
    int* rank = (int*)h1;

    hipMemsetAsync(cnt, 0, (size_t)N * 4, stream);
    hipMemsetAsync(meta, 0, 8, stream);

    k_probe<<<17, 256, 0, stream>>>(edges, (long long)2 * E,
                                    (const unsigned short*)x, meta);

    k_transpose<<<(IN_CH * HID_CH + 255) / 256, 256, 0, stream>>>(w1, w1t, IN_CH, HID_CH, meta);
    k_transpose<<<(HID_CH * OUT_CH + 255) / 256, 256, 0, stream>>>(w2, w2t, HID_CH, OUT_CH, meta);

    // CSR build (dinv needed by k_gemm2 epilogue)
    const int EB = (E + 255) / 256;
    k_count<<<EB, 256, 0, stream>>>(edges, meta, E, cnt, rank, N);
    k_scan1<<<NB, 1024, 0, stream>>>(cnt, incl, bsum, N);
    k_scan2<<<1, 64, 0, stream>>>(bsum, boff, NB);
    k_scan3<<<(N + 255) / 256, 256, 0, stream>>>(incl, cnt, boff, rowptr, N, E);
    k_dinv<<<(N + 255) / 256, 256, 0, stream>>>(cnt, dinv, N);
    k_fill<<<EB, 256, 0, stream>>>(edges, meta, E, rowptr, rank, col, N);

    // MLP
    const int MB1 = (N + 127) / 128;
    k_gemm1<<<MB1, 1024, 0, stream>>>(x, w1t, b1, h1, N, meta);
    const int MB = (N + 63) / 64;
    k_gemm2<<<MB, 256, 0, stream>>>(h1, w2t, b2, dinv, h0h, gA, N, meta);

    // 10 propagation rounds in g-space; last writes d_out
    const int PB = (N + 31) / 32;
    const _Float16* cur = gA;
    _Float16* nxt = gB;
    for (int it = 0; it < 10; ++it) {
        if (it < 9) {
            k_prop<0><<<PB, 256, 0, stream>>>(cur, h0h, rowptr, col, dinv, nxt, nullptr, N, meta);
            const _Float16* tmp = cur; cur = nxt; nxt = (_Float16*)tmp;
        } else {
            k_prop<1><<<PB, 256, 0, stream>>>(cur, h0h, rowptr, col, dinv, nullptr, d_out, N, meta);
        }
    }
}